// Round 6
// baseline (487.543 us; speedup 1.0000x reference)
//
#include <hip/hip_runtime.h>

// GenLSTM: B=8192, T=256 (255 steps), noise=8, seq_dim=4, HID=64, gates=256.
// R6: fold the x-recurrence through the gate matmul: W34 = W3@Wx[0:4] so
//   z(t+1) = h'(t)@Wh + noise(t+1)@Wxn + y2(t)@W34 + (b + b3@Wx[0:4]).
// x_new never re-enters the serial path (only the output cumsum, computed in
// the y1-phase shadow from still-live y2 regs). Noise B-frag built in-register
// from global prefetch (no LDS staging at all). Single-buffered Hb/Y1/Y2
// (write->read separated by >=2 barriers). 512 blocks x 4 waves (2 blocks/CU,
// 2 waves/SIMD), swapped-operand MFMA (weights A-frags in VGPRs, state B-frags
// from LDS, C^T out), 3 barriers/step, 7-trans cell update. LDS 6.9 KB.

typedef _Float16 h8 __attribute__((ext_vector_type(8)));
typedef __fp16 p2h __attribute__((ext_vector_type(2)));
typedef float f4 __attribute__((ext_vector_type(4)));

#define MFMA(a, b, c) __builtin_amdgcn_mfma_f32_16x16x32_f16(a, b, c, 0, 0, 0)

constexpr int SEQ = 256, STEPS = 255, ND = 8, SD = 4, HID = 64, G4 = 256;
constexpr int HST = 72;  // state row stride (f16): 16B-aligned rows

__device__ __forceinline__ void store4h(_Float16* p, f4 v) {
    p2h lo = __builtin_amdgcn_cvt_pkrtz(v[0], v[1]);
    p2h hi = __builtin_amdgcn_cvt_pkrtz(v[2], v[3]);
    float2 st;
    st.x = __builtin_bit_cast(float, lo);
    st.y = __builtin_bit_cast(float, hi);
    *(float2*)p = st;
}
// build noise B-frag: quad0 holds dims 0..3 at k=0..3, quad1 dims 4..7 at k=8..11
__device__ __forceinline__ h8 buildnf(float4 nv, int quad) {
    f4 d = {0.f, 0.f, 0.f, 0.f};
    if (quad < 2) {
        d[0] = __builtin_bit_cast(float, __builtin_amdgcn_cvt_pkrtz(nv.x, nv.y));
        d[1] = __builtin_bit_cast(float, __builtin_amdgcn_cvt_pkrtz(nv.z, nv.w));
    }
    return __builtin_bit_cast(h8, d);
}

__global__ __launch_bounds__(256, 2) void genlstm_kernel(
    const float* __restrict__ noise, const float* __restrict__ Wx,
    const float* __restrict__ Wh, const float* __restrict__ b,
    const float* __restrict__ W1, const float* __restrict__ b1,
    const float* __restrict__ W2, const float* __restrict__ b2,
    const float* __restrict__ W3, const float* __restrict__ b3,
    float* __restrict__ out)
{
    __shared__ alignas(16) _Float16 Hb[16 * HST];
    __shared__ alignas(16) _Float16 Y1b[16 * HST];
    __shared__ alignas(16) _Float16 Y2b[16 * HST];

    const int tid = threadIdx.x, wid = tid >> 6, lane = tid & 63;
    const int col = lane & 15, quad = lane >> 4, q8 = quad * 8;
    const int row0 = blockIdx.x * 16;
    const int n0 = wid * 16 + col;       // this lane's weight-out column
    const int wq = wid * 16 + quad * 4;  // C^T output-dim base

    // ---- weight A-frags -> VGPRs ----
    h8 wh[4][2], wy[4][2], wgn[4], w1f[2], w2f[2], w3f[2];
    #pragma unroll
    for (int g = 0; g < 4; ++g) {
        const int n = 64 * g + n0;
        #pragma unroll
        for (int s = 0; s < 2; ++s)
            #pragma unroll
            for (int j = 0; j < 8; ++j) {
                const int k = 32 * s + q8 + j;
                wh[g][s][j] = (_Float16)Wh[k * G4 + n];
                // W34 = W3 @ Wx[0:4]  (fp32 accumulate, single fp16 rounding)
                float acc = 0.f;
                #pragma unroll
                for (int d = 0; d < 4; ++d) acc += W3[k * SD + d] * Wx[d * G4 + n];
                wy[g][s][j] = (_Float16)acc;
            }
        // noise A-frag: k=0..3 <-> Wx rows 4..7 (quad0), k=8..11 <-> rows 8..11 (quad1)
        #pragma unroll
        for (int j = 0; j < 8; ++j) {
            float v = 0.f;
            if (quad == 0 && j < 4) v = Wx[(4 + j) * G4 + n];
            if (quad == 1 && j < 4) v = Wx[(8 + j) * G4 + n];
            wgn[g][j] = (_Float16)v;
        }
    }
    #pragma unroll
    for (int s = 0; s < 2; ++s)
        #pragma unroll
        for (int j = 0; j < 8; ++j) {
            const int k = 32 * s + q8 + j;
            w1f[s][j] = (_Float16)W1[k * HID + n0];
            w2f[s][j] = (_Float16)W2[k * HID + n0];
            w3f[s][j] = (_Float16)(col < 4 ? W3[k * SD + col] : 0.0f);
        }
    // biases by output dim (C^T): n = wq + r ; fold b3 @ Wx[0:4] into gate bias
    f4 bzv[4], b1v, b2v, b3v;
    #pragma unroll
    for (int r = 0; r < 4; ++r) {
        #pragma unroll
        for (int g = 0; g < 4; ++g) {
            float acc = b[64 * g + wq + r];
            #pragma unroll
            for (int d = 0; d < 4; ++d) acc += b3[d] * Wx[d * G4 + 64 * g + wq + r];
            bzv[g][r] = acc;
        }
        b1v[r] = b1[wq + r];
        b2v[r] = b2[wq + r];
        b3v[r] = (quad == 0) ? b3[r] : 0.0f;
    }

    // ---- LDS init (h0 = 0, y2(-1) = 0 -> x(0) contribution = 0) ----
    for (int i = tid; i < 16 * HST; i += 256) {
        Hb[i] = (_Float16)0; Y1b[i] = (_Float16)0; Y2b[i] = (_Float16)0;
    }
    if (tid < 16) {  // out[:,0,:] = 0 (cumsum starts at x0 = 0)
        float4 z; z.x = z.y = z.z = z.w = 0.0f;
        *(float4*)(out + (size_t)(row0 + tid) * SEQ * SD) = z;
    }
    __syncthreads();

    // ---- loop-invariant pointers ----
    _Float16* HbRow = &Hb[col * HST];
    _Float16* Y1row = &Y1b[col * HST];
    _Float16* Y2row = &Y2b[col * HST];
    const float* nqp = noise + ((size_t)(row0 + col) * SEQ) * ND + 4 * quad;  // quad<2
    float* outp = out + ((size_t)(row0 + col) * SEQ) * SD;  // row 'col', advanced by k

    // noise(0) frag
    float4 nv0;
    if (quad < 2) nv0 = *(const float4*)nqp;
    h8 nf = buildnf(nv0, quad);

    f4 cst = {0.f, 0.f, 0.f, 0.f}, run = {0.f, 0.f, 0.f, 0.f};
    f4 zi = bzv[0], zf = bzv[1], zg = bzv[2], zo = bzv[3];  // z(0): bias only (h0=0)
    h8 y2f0, y2f1;

    #pragma unroll 1
    for (int k = 0; k < STEPS; ++k) {
        // prefetch noise(k+1) (k+1 <= 255, in-bounds)
        float4 nv;
        nqp += ND;
        if (quad < 2) nv = *(const float4*)nqp;

        // ==== heavy phase: complete z(k), cell update, store h'(k) ====
        // noise MFMAs first (frag in regs, independent of LDS)
        zi = MFMA(wgn[0], nf, zi);
        zf = MFMA(wgn[1], nf, zf);
        zg = MFMA(wgn[2], nf, zg);
        zo = MFMA(wgn[3], nf, zo);
        // y2(k-1) slice through W34 (x-fold)
        y2f0 = *(const h8*)(Y2row + q8);
        y2f1 = *(const h8*)(Y2row + 32 + q8);
        zi = MFMA(wy[0][0], y2f0, zi); zi = MFMA(wy[0][1], y2f1, zi);
        zf = MFMA(wy[1][0], y2f0, zf); zf = MFMA(wy[1][1], y2f1, zf);
        zg = MFMA(wy[2][0], y2f0, zg); zg = MFMA(wy[2][1], y2f1, zg);
        zo = MFMA(wy[3][0], y2f0, zo); zo = MFMA(wy[3][1], y2f1, zo);
        // cell update, 7 transcendentals (shared denominators, inf-safe clamps)
        f4 hv;
        #pragma unroll
        for (int r = 0; r < 4; ++r) {
            float Ei = __expf(-fmaxf(zi[r], -15.f));
            float Ef = __expf(-fmaxf(zf[r], -15.f));
            float Eg = __expf(-2.f * fmaxf(zg[r], -15.f));
            float Eo = __expf(-zo[r]);
            float Di = 1.f + Ei, Df = 1.f + Ef, Dg = 1.f + Eg, Do = 1.f + Eo;
            float DiDg = Di * Dg;
            float cn = (cst[r] * DiDg + (2.f - Dg) * Df) *
                       __builtin_amdgcn_rcpf(Df * DiDg);
            cst[r] = cn;
            float Ec = __expf(-2.f * fmaxf(cn, -15.f));
            hv[r] = (1.f - Ec) * __builtin_amdgcn_rcpf(Do * (1.f + Ec));
        }
        store4h(HbRow + wq, hv);  // h'(k)
        __syncthreads();  // B1

        // ==== y1 phase (+ shadow: x-out(k-1), gate-h MFMAs for z(k+1)) ====
        h8 h0 = *(const h8*)(HbRow + q8);
        h8 h1 = *(const h8*)(HbRow + 32 + q8);
        f4 y1 = b1v;
        y1 = MFMA(w1f[0], h0, y1);
        y1 = MFMA(w1f[1], h1, y1);
        // x_new(k-1) = y2(k-1)@W3 + b3 (regs still live) -> cumsum out[k]
        f4 x = b3v;
        x = MFMA(w3f[0], y2f0, x);
        x = MFMA(w3f[1], y2f1, x);
        // pipelined gate-h for z(k+1)
        zi = bzv[0]; zi = MFMA(wh[0][0], h0, zi); zi = MFMA(wh[0][1], h1, zi);
        zf = bzv[1]; zf = MFMA(wh[1][0], h0, zf); zf = MFMA(wh[1][1], h1, zf);
        zg = bzv[2]; zg = MFMA(wh[2][0], h0, zg); zg = MFMA(wh[2][1], h1, zg);
        zo = bzv[3]; zo = MFMA(wh[3][0], h0, zo); zo = MFMA(wh[3][1], h1, zo);
        #pragma unroll
        for (int r = 0; r < 4; ++r) y1[r] = fmaxf(y1[r], 0.0f);
        store4h(Y1row + wq, y1);
        if (k > 0 && wid == 0 && quad == 0) {
            run += x;
            *(f4*)(outp + (size_t)k * SD) = run;
        }
        __syncthreads();  // B2

        // ==== y2 phase ====
        h8 p0 = *(const h8*)(Y1row + q8);
        h8 p1 = *(const h8*)(Y1row + 32 + q8);
        f4 y2 = b2v;
        y2 = MFMA(w2f[0], p0, y2);
        y2 = MFMA(w2f[1], p1, y2);
        #pragma unroll
        for (int r = 0; r < 4; ++r) y2[r] = fmaxf(y2[r], 0.0f);
        store4h(Y2row + wq, y2);
        nf = buildnf(nv, quad);  // noise frag for next heavy phase
        __syncthreads();  // B3
    }

    // tail: x_new(254) from y2(254) -> out[255]
    y2f0 = *(const h8*)(Y2row + q8);
    y2f1 = *(const h8*)(Y2row + 32 + q8);
    f4 x = b3v;
    x = MFMA(w3f[0], y2f0, x);
    x = MFMA(w3f[1], y2f1, x);
    if (wid == 0 && quad == 0) {
        run += x;
        *(f4*)(outp + (size_t)STEPS * SD) = run;
    }
}

extern "C" void kernel_launch(void* const* d_in, const int* in_sizes, int n_in,
                              void* d_out, int out_size, void* d_ws, size_t ws_size,
                              hipStream_t stream) {
    genlstm_kernel<<<512, 256, 0, stream>>>(
        (const float*)d_in[0], (const float*)d_in[1], (const float*)d_in[2],
        (const float*)d_in[3], (const float*)d_in[4], (const float*)d_in[5],
        (const float*)d_in[6], (const float*)d_in[7], (const float*)d_in[8],
        (const float*)d_in[9], (float*)d_out);
}